// Round 8
// baseline (4012.034 us; speedup 1.0000x reference)
//
#include <hip/hip_runtime.h>

#define S_LEN 768
#define EMB   128
#define HDIM  256
#define GATES 1024
#define MLP   128
#define SENT  0xAAAAAAAAu

// 16B poll load at AGENT scope (sc1) — same cache behavior per word as the
// compiler's relaxed __hip_atomic_load(AGENT) (global_load_dword sc1), but
// 4 words per instruction. Evidence for the scope decode: sc0-only loads
// never see remote stores (R2 hang); sc0+sc1 = system scope, bypasses MALL
// and storms DRAM (R6 WRITE_SIZE blowup); plain atomic (sc1) works (R3/R5).
__device__ __forceinline__ float4 ld16_agent(const void* p) {
    float4 v;
    asm volatile("global_load_dwordx4 %0, %1, off sc1\n\ts_waitcnt vmcnt(0)"
                 : "=v"(v) : "v"(p) : "memory");
    return v;
}

// ---------------- embedding gather ----------------
__global__ void embed_kernel(const int* __restrict__ widx, const int* __restrict__ pidx,
                             const float* __restrict__ Ww, const float* __restrict__ Wp,
                             float* __restrict__ x0) {
    int t = blockIdx.x, k = threadIdx.x;
    float v;
    if (k < 100) v = Ww[widx[t] * 100 + k];
    else         v = Wp[pidx[t] * 28 + (k - 100)];
    x0[t * EMB + k] = v;
}

// ---------------- generic fp32 GEMM: C[M,N] = A[M,*] * B[N,*]^T + bias1 + bias2 ----------------
__global__ __launch_bounds__(256) void gemm_bias(
    const float* __restrict__ A, int lda,
    const float* __restrict__ B, int ldb,
    const float* __restrict__ bias1, const float* __restrict__ bias2,
    float* __restrict__ C, int ldc, int K) {
    __shared__ float As[32][65];
    __shared__ float Bs[32][65];
    const int t  = threadIdx.x;
    const int m0 = blockIdx.x * 64, n0 = blockIdx.y * 64;
    const int tm = t >> 4, tn = t & 15;
    float acc[4][4];
#pragma unroll
    for (int i = 0; i < 4; ++i)
#pragma unroll
        for (int j = 0; j < 4; ++j) acc[i][j] = 0.f;

    for (int k0 = 0; k0 < K; k0 += 32) {
#pragma unroll
        for (int l = 0; l < 8; ++l) {
            int idx = t + l * 256;
            int m = idx >> 5, kk = idx & 31;
            As[kk][m] = A[(m0 + m) * lda + k0 + kk];
            Bs[kk][m] = B[(n0 + m) * ldb + k0 + kk];
        }
        __syncthreads();
#pragma unroll
        for (int kk = 0; kk < 32; ++kk) {
            float a4[4], b4[4];
#pragma unroll
            for (int i = 0; i < 4; ++i) a4[i] = As[kk][tm * 4 + i];
#pragma unroll
            for (int j = 0; j < 4; ++j) b4[j] = Bs[kk][tn * 4 + j];
#pragma unroll
            for (int i = 0; i < 4; ++i)
#pragma unroll
                for (int j = 0; j < 4; ++j)
                    acc[i][j] = fmaf(a4[i], b4[j], acc[i][j]);
        }
        __syncthreads();
    }
    float bb[4];
#pragma unroll
    for (int j = 0; j < 4; ++j) {
        int n = n0 + tn * 4 + j;
        bb[j] = (bias1 ? bias1[n] : 0.f) + (bias2 ? bias2[n] : 0.f);
    }
#pragma unroll
    for (int i = 0; i < 4; ++i) {
        int m = m0 + tm * 4 + i;
        float4 o;
        o.x = acc[i][0] + bb[0];
        o.y = acc[i][1] + bb[1];
        o.z = acc[i][2] + bb[2];
        o.w = acc[i][3] + bb[3];
        *(float4*)(&C[m * ldc + n0 + tn * 4]) = o;
    }
}

// ---------------- LSTM recurrence, one layer, both directions ----------------
// 64 blocks x 256 threads: dir = bid&1, slice sl = bid>>1 (32 slices/dir).
// Block owns 8 h-outputs. Row map: lr = e*4 + gate, 8 lanes/row -> all 4
// gate sums of an output in one wave (shfl gather, no 2nd barrier).
// 32KB Whh slice staged once in static LDS (R5-proven residency).
// Sync: data-as-flag (h word != 0xAA). Wave 0 polls with dwordx4 sc1
// (agent scope, 16x fewer poll ops than R5's 256-thread atomic poll).
// Rescue after 256 spins: proven per-word atomic poll. hps double-buffered,
// swizzled -> conflict-free; ONE barrier per step.
__global__ __launch_bounds__(256, 1) void lstm_rec(
    const float* __restrict__ WhhF, const float* __restrict__ WhhB,
    const float* __restrict__ gxF, const float* __restrict__ gxB,
    float* __restrict__ hOut)        // [S][512]; fwd cols 0..255, bwd 256..511
{
    __shared__ float4 wlds[8 * 256];     // 32KB: [i][tid]
    __shared__ float4 hps[2][64];        // double-buffered swizzled h_prev
    const int tid = threadIdx.x;
    const int dir = blockIdx.x & 1;
    const int sl  = blockIdx.x >> 1;
    const float* __restrict__ Whh = dir ? WhhB : WhhF;
    const float* __restrict__ gx  = dir ? gxB  : gxF;
    unsigned int* hbits = (unsigned int*)hOut;

    const int lr = tid >> 3, q = tid & 7;               // row 0..31, chunk 0..7
    const int grow = (lr & 3) * 256 + sl * 8 + (lr >> 2);  // gate*256 + sl*8 + e

    // stage Whh slice into LDS
    {
        const float4* Wg = (const float4*)(Whh + grow * HDIM + q * 32);
#pragma unroll
        for (int i = 0; i < 8; ++i) wlds[i * 256 + tid] = Wg[i];
    }

    float creg = 0.f;                                   // c-state (owner lanes)
    float gval = (q == 0) ? gx[(dir ? (S_LEN - 1) : 0) * GATES + grow] : 0.f;

    for (int t = 0; t < S_LEN; ++t) {
        const int tp = dir ? (S_LEN - 1 - t) : t;
        const int buf = t & 1;
        if (tid < 64) {
            float4 b = {0.f, 0.f, 0.f, 0.f};
            if (t > 0) {
                const int tpp = dir ? (tp + 1) : (tp - 1);
                const unsigned int* pw = hbits + tpp * 512 + dir * HDIM + tid * 4;
                int spin = 0;
                for (;;) {
                    b = ld16_agent(pw);
                    if (__float_as_uint(b.x) != SENT && __float_as_uint(b.y) != SENT &&
                        __float_as_uint(b.z) != SENT && __float_as_uint(b.w) != SENT)
                        break;
                    if (++spin >= 256) {    // rescue: proven per-word atomic poll
                        float* bb = &b.x;
#pragma unroll
                        for (int k = 0; k < 4; ++k) {
                            unsigned int v = __float_as_uint(bb[k]);
                            while (v == SENT)
                                v = __hip_atomic_load(pw + k, __ATOMIC_RELAXED,
                                                      __HIP_MEMORY_SCOPE_AGENT);
                            bb[k] = __uint_as_float(v);
                        }
                        break;
                    }
                }
            }
            // swizzled store: logical float4 j=tid -> slot 8*(j>>3) + ((j&7)^(j>>3))
            hps[buf][8 * (tid >> 3) + ((tid & 7) ^ (tid >> 3))] = b;
        }
        __syncthreads();   // ONE barrier/step (double-buffered hps)

        // prefetch next step's gx (independent of h -> overlaps compute)
        float gnext = 0.f;
        if (q == 0 && t + 1 < S_LEN) {
            const int tpn = dir ? (tp - 1) : (tp + 1);
            gnext = gx[tpn * GATES + grow];
        }

        const float4* hb = hps[buf];
        float4 a = {0.f, 0.f, 0.f, 0.f};
#pragma unroll
        for (int i = 0; i < 8; ++i) {
            float4 wv = wlds[i * 256 + tid];
            float4 hv = hb[8 * q + (i ^ q)];
            a.x = fmaf(wv.x, hv.x, a.x);
            a.y = fmaf(wv.y, hv.y, a.y);
            a.z = fmaf(wv.z, hv.z, a.z);
            a.w = fmaf(wv.w, hv.w, a.w);
        }
        float acc = (a.x + a.y) + (a.z + a.w);
        acc += __shfl_xor(acc, 1);
        acc += __shfl_xor(acc, 2);
        acc += __shfl_xor(acc, 4);
        if (q == 0) acc += gval;          // q0 lanes hold full row sums

        // gather the 4 gate rows of this wave's outputs from the q=0 lanes
        const int base = tid & 32;
        float gi = __shfl(acc, base + 0);
        float gf = __shfl(acc, base + 8);
        float gg = __shfl(acc, base + 16);
        float go = __shfl(acc, base + 24);

        if ((tid & 31) == 0) {            // 8 owner lanes, spread over 4 waves
            float si = __fdividef(1.f, 1.f + __expf(-gi));
            float sf = __fdividef(1.f, 1.f + __expf(-gf));
            float so = __fdividef(1.f, 1.f + __expf(-go));
            float eg = __expf(2.f * gg);
            float tg = 1.f - __fdividef(2.f, eg + 1.f);
            creg = fmaf(sf, creg, si * tg);
            float ec = __expf(2.f * creg);
            float tc = 1.f - __fdividef(2.f, ec + 1.f);
            float hv = so * tc;
            unsigned int ob = __float_as_uint(hv);
            if (ob == SENT) ob ^= 1u;     // never store the sentinel
            const int e = tid >> 5;
            __hip_atomic_store(&hbits[tp * 512 + dir * HDIM + sl * 8 + e], ob,
                               __ATOMIC_RELAXED, __HIP_MEMORY_SCOPE_AGENT);
        }
        gval = gnext;
    }
}

// ---------------- pairwise scorer ----------------
__device__ __forceinline__ float tanh_fast(float x) {
    float e = __expf(2.f * x);
    return 1.f - __fdividef(2.f, e + 1.f);
}

__global__ __launch_bounds__(256) void scorer(
    const float* __restrict__ hA, const float* __restrict__ hB,
    const float* __restrict__ w2, const float* __restrict__ b2,
    float* __restrict__ out) {
    __shared__ float Al[32][129];
    __shared__ float Bl[32][129];
    __shared__ float w2s[128];
    const int t  = threadIdx.x;
    const int i0 = blockIdx.x * 32, j0 = blockIdx.y * 32;
    for (int idx = t; idx < 32 * 128; idx += 256) {
        int r = idx >> 7, k = idx & 127;
        Al[r][k] = hA[(i0 + r) * MLP + k];
        Bl[r][k] = hB[(j0 + r) * MLP + k];
    }
    if (t < 128) w2s[t] = w2[t];
    __syncthreads();

    const int j = t & 31, i2 = t >> 5;
    const float base = b2[0];
    float acc0 = base, acc1 = base, acc2 = base, acc3 = base;
#pragma unroll 4
    for (int k = 0; k < 128; ++k) {
        float bv = Bl[j][k];
        float wv = w2s[k];
        float y0 = Al[i2 * 4 + 0][k] + bv;
        float y1 = Al[i2 * 4 + 1][k] + bv;
        float y2 = Al[i2 * 4 + 2][k] + bv;
        float y3 = Al[i2 * 4 + 3][k] + bv;
        acc0 = fmaf(wv, tanh_fast(y0), acc0);
        acc1 = fmaf(wv, tanh_fast(y1), acc1);
        acc2 = fmaf(wv, tanh_fast(y2), acc2);
        acc3 = fmaf(wv, tanh_fast(y3), acc3);
    }
    const int jj = j0 + j;
    float accs[4] = {acc0, acc1, acc2, acc3};
#pragma unroll
    for (int ii = 0; ii < 4; ++ii) {
        int i = i0 + i2 * 4 + ii;
        out[i * S_LEN + jj] = (i == jj) ? 0.f : accs[ii];
    }
}

extern "C" void kernel_launch(void* const* d_in, const int* in_sizes, int n_in,
                              void* d_out, int out_size, void* d_ws, size_t ws_size,
                              hipStream_t stream) {
    (void)in_sizes; (void)n_in; (void)out_size; (void)ws_size;
    const int*   widx  = (const int*)d_in[0];
    const int*   pidx  = (const int*)d_in[1];
    const float* Ww    = (const float*)d_in[3];
    const float* Wp    = (const float*)d_in[4];
    const float* Wih0f = (const float*)d_in[5];
    const float* Whh0f = (const float*)d_in[6];
    const float* bih0f = (const float*)d_in[7];
    const float* bhh0f = (const float*)d_in[8];
    const float* Wih0b = (const float*)d_in[9];
    const float* Whh0b = (const float*)d_in[10];
    const float* bih0b = (const float*)d_in[11];
    const float* bhh0b = (const float*)d_in[12];
    const float* Wih1f = (const float*)d_in[13];
    const float* Whh1f = (const float*)d_in[14];
    const float* bih1f = (const float*)d_in[15];
    const float* bhh1f = (const float*)d_in[16];
    const float* Wih1b = (const float*)d_in[17];
    const float* Whh1b = (const float*)d_in[18];
    const float* bih1b = (const float*)d_in[19];
    const float* bhh1b = (const float*)d_in[20];
    const float* W1    = (const float*)d_in[21];
    const float* b1    = (const float*)d_in[22];
    const float* W2    = (const float*)d_in[23];
    const float* b2    = (const float*)d_in[24];

    float* ws  = (float*)d_ws;
    float* x0  = ws;                       // 768*128
    float* h0  = x0 + S_LEN * EMB;         // 768*512
    float* h1  = h0 + S_LEN * 512;         // 768*512
    float* gxf = h1 + S_LEN * 512;         // 768*1024
    float* gxb = gxf + S_LEN * GATES;      // 768*1024
    float* hA  = gxb + S_LEN * GATES;      // 768*128
    float* hB  = hA + S_LEN * MLP;         // 768*128

    // sentinel-fill h0 and h1 (contiguous) — the data-as-flag ready marker
    hipMemsetAsync(h0, 0xAA, 2 * S_LEN * 512 * sizeof(float), stream);

    embed_kernel<<<S_LEN, EMB, 0, stream>>>(widx, pidx, Ww, Wp, x0);

    dim3 gg(12, 16);
    gemm_bias<<<gg, 256, 0, stream>>>(x0, EMB, Wih0f, EMB, bih0f, bhh0f, gxf, GATES, EMB);
    gemm_bias<<<gg, 256, 0, stream>>>(x0, EMB, Wih0b, EMB, bih0b, bhh0b, gxb, GATES, EMB);
    lstm_rec<<<64, 256, 0, stream>>>(Whh0f, Whh0b, gxf, gxb, h0);

    gemm_bias<<<gg, 256, 0, stream>>>(h0, 512, Wih1f, 512, bih1f, bhh1f, gxf, GATES, 512);
    gemm_bias<<<gg, 256, 0, stream>>>(h0, 512, Wih1b, 512, bih1b, bhh1b, gxb, GATES, 512);
    lstm_rec<<<64, 256, 0, stream>>>(Whh1f, Whh1b, gxf, gxb, h1);

    dim3 ga(12, 2);
    gemm_bias<<<ga, 256, 0, stream>>>(h1, 512, W1,       1024, b1,      nullptr, hA, MLP, 512);
    gemm_bias<<<ga, 256, 0, stream>>>(h1, 512, W1 + 512, 1024, nullptr, nullptr, hB, MLP, 512);

    dim3 gs(24, 24);
    scorer<<<gs, 256, 0, stream>>>(hA, hB, W2, b2, (float*)d_out);
}

// Round 9
// 3276.587 us; speedup vs baseline: 1.2245x; 1.2245x over previous
//
#include <hip/hip_runtime.h>

#define S_LEN 768
#define EMB   128
#define HDIM  256
#define GATES 1024
#define MLP   128
#define SENT  0xAAAAAAAAu
#define NREP  8
#define REPSZ (S_LEN * 512)

// ---------------- embedding gather ----------------
__global__ void embed_kernel(const int* __restrict__ widx, const int* __restrict__ pidx,
                             const float* __restrict__ Ww, const float* __restrict__ Wp,
                             float* __restrict__ x0) {
    int t = blockIdx.x, k = threadIdx.x;
    float v;
    if (k < 100) v = Ww[widx[t] * 100 + k];
    else         v = Wp[pidx[t] * 28 + (k - 100)];
    x0[t * EMB + k] = v;
}

// ---------------- generic fp32 GEMM: C[M,N] = A[M,*] * B[N,*]^T + bias1 + bias2 ----------------
__global__ __launch_bounds__(256) void gemm_bias(
    const float* __restrict__ A, int lda,
    const float* __restrict__ B, int ldb,
    const float* __restrict__ bias1, const float* __restrict__ bias2,
    float* __restrict__ C, int ldc, int K) {
    __shared__ float As[32][65];
    __shared__ float Bs[32][65];
    const int t  = threadIdx.x;
    const int m0 = blockIdx.x * 64, n0 = blockIdx.y * 64;
    const int tm = t >> 4, tn = t & 15;
    float acc[4][4];
#pragma unroll
    for (int i = 0; i < 4; ++i)
#pragma unroll
        for (int j = 0; j < 4; ++j) acc[i][j] = 0.f;

    for (int k0 = 0; k0 < K; k0 += 32) {
#pragma unroll
        for (int l = 0; l < 8; ++l) {
            int idx = t + l * 256;
            int m = idx >> 5, kk = idx & 31;
            As[kk][m] = A[(m0 + m) * lda + k0 + kk];
            Bs[kk][m] = B[(n0 + m) * ldb + k0 + kk];
        }
        __syncthreads();
#pragma unroll
        for (int kk = 0; kk < 32; ++kk) {
            float a4[4], b4[4];
#pragma unroll
            for (int i = 0; i < 4; ++i) a4[i] = As[kk][tm * 4 + i];
#pragma unroll
            for (int j = 0; j < 4; ++j) b4[j] = Bs[kk][tn * 4 + j];
#pragma unroll
            for (int i = 0; i < 4; ++i)
#pragma unroll
                for (int j = 0; j < 4; ++j)
                    acc[i][j] = fmaf(a4[i], b4[j], acc[i][j]);
        }
        __syncthreads();
    }
    float bb[4];
#pragma unroll
    for (int j = 0; j < 4; ++j) {
        int n = n0 + tn * 4 + j;
        bb[j] = (bias1 ? bias1[n] : 0.f) + (bias2 ? bias2[n] : 0.f);
    }
#pragma unroll
    for (int i = 0; i < 4; ++i) {
        int m = m0 + tm * 4 + i;
        float4 o;
        o.x = acc[i][0] + bb[0];
        o.y = acc[i][1] + bb[1];
        o.z = acc[i][2] + bb[2];
        o.w = acc[i][3] + bb[3];
        *(float4*)(&C[m * ldc + n0 + tn * 4]) = o;
    }
}

// ---------------- LSTM recurrence, one layer, both directions ----------------
// 64 blocks x 256 threads: dir = bid&1, slice sl = bid>>1 (32 slices/dir).
// Block owns 8 h-outputs. Row map: lr = e*4 + gate -> all 4 gate sums of an
// output in one wave (shfl gather, single barrier/step). 32KB Whh slice in
// static LDS (R5-proven). Sync: data-as-flag with REPLICATED flag lines —
// producers publish each h value to NREP replica buffers (relaxed agent
// atomic stores, fire-and-forget); consumer block sl polls ONLY replica
// sl&7 with per-thread relaxed agent atomic loads (the one poll instrument
// that is clean at the IF: R2 sc0=never-visible, R6/R8 sc1-vector-load =
// DRAM RTs + writeback storms, R5 atomic = clean). Per-line pollers drop
// 512 -> 64, below R3's outlier-free level.
__global__ __launch_bounds__(256, 1) void lstm_rec(
    const float* __restrict__ WhhF, const float* __restrict__ WhhB,
    const float* __restrict__ gxF, const float* __restrict__ gxB,
    float* __restrict__ hOut,            // [S][512] plain output for next GEMMs
    unsigned int* __restrict__ hrep)     // [NREP][S][512] replicated flags
{
    __shared__ float4 wlds[8 * 256];     // 32KB: [i][tid]
    __shared__ float4 hps[2][64];        // double-buffered swizzled h_prev
    const int tid = threadIdx.x;
    const int dir = blockIdx.x & 1;
    const int sl  = blockIdx.x >> 1;
    const float* __restrict__ Whh = dir ? WhhB : WhhF;
    const float* __restrict__ gx  = dir ? gxB  : gxF;

    const int lr = tid >> 3, q = tid & 7;                  // row 0..31, chunk 0..7
    const int grow = (lr & 3) * 256 + sl * 8 + (lr >> 2);  // gate*256 + sl*8 + e

    // stage Whh slice into LDS (one-time)
    {
        const float4* Wg = (const float4*)(Whh + grow * HDIM + q * 32);
#pragma unroll
        for (int i = 0; i < 8; ++i) wlds[i * 256 + tid] = Wg[i];
    }

    float creg = 0.f;                                      // c-state (owner lanes)
    float gval = (q == 0) ? gx[(dir ? (S_LEN - 1) : 0) * GATES + grow] : 0.f;

    const unsigned int* myrep = hrep + (sl & (NREP - 1)) * REPSZ;

    for (int t = 0; t < S_LEN; ++t) {
        const int tp = dir ? (S_LEN - 1 - t) : t;
        const int buf = t & 1;
        {
            float hv = 0.f;
            if (t > 0) {
                const int tpp = dir ? (tp + 1) : (tp - 1);
                const unsigned int* pw = myrep + tpp * 512 + dir * HDIM + tid;
                unsigned int v = __hip_atomic_load(pw, __ATOMIC_RELAXED,
                                                   __HIP_MEMORY_SCOPE_AGENT);
                while (v == SENT)
                    v = __hip_atomic_load(pw, __ATOMIC_RELAXED,
                                          __HIP_MEMORY_SCOPE_AGENT);
                hv = __uint_as_float(v);
            }
            // swizzled store: logical float4 j=tid>>2 -> slot 8*(j>>3)+((j&7)^(j>>3))
            const int j = tid >> 2;
            const int slot = 8 * (j >> 3) + ((j & 7) ^ (j >> 3));
            ((float*)hps[buf])[slot * 4 + (tid & 3)] = hv;
        }
        __syncthreads();   // ONE barrier/step (double-buffered hps)

        // prefetch next step's gx (independent of h -> overlaps compute)
        float gnext = 0.f;
        if (q == 0 && t + 1 < S_LEN) {
            const int tpn = dir ? (tp - 1) : (tp + 1);
            gnext = gx[tpn * GATES + grow];
        }

        const float4* hb = hps[buf];
        float4 a = {0.f, 0.f, 0.f, 0.f};
#pragma unroll
        for (int i = 0; i < 8; ++i) {
            float4 wv = wlds[i * 256 + tid];
            float4 hv = hb[8 * q + (i ^ q)];
            a.x = fmaf(wv.x, hv.x, a.x);
            a.y = fmaf(wv.y, hv.y, a.y);
            a.z = fmaf(wv.z, hv.z, a.z);
            a.w = fmaf(wv.w, hv.w, a.w);
        }
        float acc = (a.x + a.y) + (a.z + a.w);
        acc += __shfl_xor(acc, 1);
        acc += __shfl_xor(acc, 2);
        acc += __shfl_xor(acc, 4);
        if (q == 0) acc += gval;          // q0 lanes hold full row sums

        // gather the 4 gate rows of this wave's outputs from the q=0 lanes
        const int base = tid & 32;
        float gi = __shfl(acc, base + 0);
        float gf = __shfl(acc, base + 8);
        float gg = __shfl(acc, base + 16);
        float go = __shfl(acc, base + 24);

        if ((tid & 31) == 0) {            // 8 owner lanes, spread over 4 waves
            float si = __fdividef(1.f, 1.f + __expf(-gi));
            float sf = __fdividef(1.f, 1.f + __expf(-gf));
            float so = __fdividef(1.f, 1.f + __expf(-go));
            float eg = __expf(2.f * gg);
            float tg = 1.f - __fdividef(2.f, eg + 1.f);
            creg = fmaf(sf, creg, si * tg);
            float ec = __expf(2.f * creg);
            float tc = 1.f - __fdividef(2.f, ec + 1.f);
            float hv = so * tc;
            unsigned int ob = __float_as_uint(hv);
            if (ob == SENT) ob ^= 1u;     // never store the sentinel
            const int e = tid >> 5;
            const int col = dir * HDIM + sl * 8 + e;
            hOut[tp * 512 + col] = __uint_as_float(ob);   // plain: next dispatches
            unsigned int* rp = hrep + tp * 512 + col;
#pragma unroll
            for (int r = 0; r < NREP; ++r)                // replicate the flag
                __hip_atomic_store(rp + r * REPSZ, ob, __ATOMIC_RELAXED,
                                   __HIP_MEMORY_SCOPE_AGENT);
        }
        gval = gnext;
    }
}

// ---------------- pairwise scorer ----------------
__device__ __forceinline__ float tanh_fast(float x) {
    float e = __expf(2.f * x);
    return 1.f - __fdividef(2.f, e + 1.f);
}

__global__ __launch_bounds__(256) void scorer(
    const float* __restrict__ hA, const float* __restrict__ hB,
    const float* __restrict__ w2, const float* __restrict__ b2,
    float* __restrict__ out) {
    __shared__ float Al[32][129];
    __shared__ float Bl[32][129];
    __shared__ float w2s[128];
    const int t  = threadIdx.x;
    const int i0 = blockIdx.x * 32, j0 = blockIdx.y * 32;
    for (int idx = t; idx < 32 * 128; idx += 256) {
        int r = idx >> 7, k = idx & 127;
        Al[r][k] = hA[(i0 + r) * MLP + k];
        Bl[r][k] = hB[(j0 + r) * MLP + k];
    }
    if (t < 128) w2s[t] = w2[t];
    __syncthreads();

    const int j = t & 31, i2 = t >> 5;
    const float base = b2[0];
    float acc0 = base, acc1 = base, acc2 = base, acc3 = base;
#pragma unroll 4
    for (int k = 0; k < 128; ++k) {
        float bv = Bl[j][k];
        float wv = w2s[k];
        float y0 = Al[i2 * 4 + 0][k] + bv;
        float y1 = Al[i2 * 4 + 1][k] + bv;
        float y2 = Al[i2 * 4 + 2][k] + bv;
        float y3 = Al[i2 * 4 + 3][k] + bv;
        acc0 = fmaf(wv, tanh_fast(y0), acc0);
        acc1 = fmaf(wv, tanh_fast(y1), acc1);
        acc2 = fmaf(wv, tanh_fast(y2), acc2);
        acc3 = fmaf(wv, tanh_fast(y3), acc3);
    }
    const int jj = j0 + j;
    float accs[4] = {acc0, acc1, acc2, acc3};
#pragma unroll
    for (int ii = 0; ii < 4; ++ii) {
        int i = i0 + i2 * 4 + ii;
        out[i * S_LEN + jj] = (i == jj) ? 0.f : accs[ii];
    }
}

extern "C" void kernel_launch(void* const* d_in, const int* in_sizes, int n_in,
                              void* d_out, int out_size, void* d_ws, size_t ws_size,
                              hipStream_t stream) {
    (void)in_sizes; (void)n_in; (void)out_size; (void)ws_size;
    const int*   widx  = (const int*)d_in[0];
    const int*   pidx  = (const int*)d_in[1];
    const float* Ww    = (const float*)d_in[3];
    const float* Wp    = (const float*)d_in[4];
    const float* Wih0f = (const float*)d_in[5];
    const float* Whh0f = (const float*)d_in[6];
    const float* bih0f = (const float*)d_in[7];
    const float* bhh0f = (const float*)d_in[8];
    const float* Wih0b = (const float*)d_in[9];
    const float* Whh0b = (const float*)d_in[10];
    const float* bih0b = (const float*)d_in[11];
    const float* bhh0b = (const float*)d_in[12];
    const float* Wih1f = (const float*)d_in[13];
    const float* Whh1f = (const float*)d_in[14];
    const float* bih1f = (const float*)d_in[15];
    const float* bhh1f = (const float*)d_in[16];
    const float* Wih1b = (const float*)d_in[17];
    const float* Whh1b = (const float*)d_in[18];
    const float* bih1b = (const float*)d_in[19];
    const float* bhh1b = (const float*)d_in[20];
    const float* W1    = (const float*)d_in[21];
    const float* b1    = (const float*)d_in[22];
    const float* W2    = (const float*)d_in[23];
    const float* b2    = (const float*)d_in[24];

    float* ws  = (float*)d_ws;
    float* x0  = ws;                       // 768*128
    float* h0  = x0 + S_LEN * EMB;         // 768*512
    float* h1  = h0 + S_LEN * 512;         // 768*512
    float* gxf = h1 + S_LEN * 512;         // 768*1024
    float* gxb = gxf + S_LEN * GATES;      // 768*1024
    float* hA  = gxb + S_LEN * GATES;      // 768*128
    float* hB  = hA + S_LEN * MLP;         // 768*128
    unsigned int* hrep = (unsigned int*)(hB + S_LEN * MLP);  // [NREP][S][512]

    embed_kernel<<<S_LEN, EMB, 0, stream>>>(widx, pidx, Ww, Wp, x0);

    dim3 gg(12, 16);
    // layer 0
    hipMemsetAsync(hrep, 0xAA, (size_t)NREP * REPSZ * sizeof(unsigned int), stream);
    gemm_bias<<<gg, 256, 0, stream>>>(x0, EMB, Wih0f, EMB, bih0f, bhh0f, gxf, GATES, EMB);
    gemm_bias<<<gg, 256, 0, stream>>>(x0, EMB, Wih0b, EMB, bih0b, bhh0b, gxb, GATES, EMB);
    lstm_rec<<<64, 256, 0, stream>>>(Whh0f, Whh0b, gxf, gxb, h0, hrep);

    // layer 1 (re-sentinel the replicated flags first)
    hipMemsetAsync(hrep, 0xAA, (size_t)NREP * REPSZ * sizeof(unsigned int), stream);
    gemm_bias<<<gg, 256, 0, stream>>>(h0, 512, Wih1f, 512, bih1f, bhh1f, gxf, GATES, 512);
    gemm_bias<<<gg, 256, 0, stream>>>(h0, 512, Wih1b, 512, bih1b, bhh1b, gxb, GATES, 512);
    lstm_rec<<<64, 256, 0, stream>>>(Whh1f, Whh1b, gxf, gxb, h1, hrep);

    dim3 ga(12, 2);
    gemm_bias<<<ga, 256, 0, stream>>>(h1, 512, W1,       1024, b1,      nullptr, hA, MLP, 512);
    gemm_bias<<<ga, 256, 0, stream>>>(h1, 512, W1 + 512, 1024, nullptr, nullptr, hB, MLP, 512);

    dim3 gs(24, 24);
    scorer<<<gs, 256, 0, stream>>>(hA, hB, W2, b2, (float*)d_out);
}